// Round 6
// baseline (14998.448 us; speedup 1.0000x reference)
//
#include <hip/hip_runtime.h>
#include <math.h>

#define Tn 64
#define Bn 32
#define INn 64
#define Nn 512
#define WDn 64
#define Rn 4
#define Hn 256
#define G4H 1024
#define OUTn 64
#define IFn 471
#define CLIPV 20.0f
#define EPSV 1e-6f

#define OFF_RKEY 0
#define OFF_RSTR 256
#define OFF_WKEY 260
#define OFF_WSTR 324
#define OFF_ERASE 325
#define OFF_WVEC 389
#define OFF_FREE 453
#define OFF_AG 457
#define OFF_WG 458
#define OFF_MODES 459

// ---------------- persistent device state ----------------
__device__ float S_h[2][Bn][Hn];          // h(t) in slot t&1
__device__ float S_c[2][Bn][Hn];
__device__ float S_gates[2][Bn][G4H];     // raw gates(t) in slot t&1
__device__ float S_mem[Bn][Nn][WDn];
__device__ float S_rw[Bn][Rn][Nn];
__device__ float S_ww[2][Bn][Nn];
__device__ float S_link[Bn][Nn][Nn];
__device__ float S_prec[2][Bn][Nn];
__device__ float S_usage[2][Bn][Nn];
__device__ float S_reads[Bn][Rn][WDn];
__device__ float S_itf[Bn][IFn];
__device__ float S_rc[Bn][Rn][Nn];
__device__ float S_fw[Bn][Rn][Nn];
__device__ float S_bwp[Bn][8][Rn*Nn];
__device__ float S_sumww[Bn];
// monotonic flags
__device__ unsigned int g_hh;             // 32*(t+1) when all h(t) written
__device__ unsigned int g_ww[Bn];         // t+1 when ww(t) ready
__device__ unsigned int g_rc[Bn];         // t+1 when phaseA(t) fully done
__device__ unsigned int g_ld[Bn];         // 8*(t+1) when link(t) done
__device__ unsigned int g_fb[Bn];         // t+1 when finalize(t) done
__device__ unsigned int g_fin;            // 32*(t+1) when all finalize(t) done
__device__ unsigned int g_gate;           // 16*(t+1) when gates(t) ready

// ---------------- helpers ----------------
__device__ __forceinline__ float sigm(float x){ return 1.f/(1.f+expf(-x)); }
__device__ __forceinline__ float clipv(float x){ return fminf(fmaxf(x,-CLIPV),CLIPV); }
__device__ __forceinline__ float oneplusf(float x){
  float sp = (x > 0.f) ? (x + log1pf(expf(-x))) : log1pf(expf(x));
  return 1.f + sp;
}
__device__ __forceinline__ float wredsum(float v){
  #pragma unroll
  for (int o=32;o>0;o>>=1) v += __shfl_xor(v,o,64);
  return v;
}
__device__ __forceinline__ float bredsum(float v, volatile float* scr){
  v = wredsum(v);
  if ((threadIdx.x & 63) == 0) scr[threadIdx.x >> 6] = v;
  __syncthreads();
  float s = scr[0];
  #pragma unroll
  for (int i=1;i<8;i++) s += scr[i];
  __syncthreads();
  return s;
}
__device__ __forceinline__ float bredmax(float v, volatile float* scr){
  #pragma unroll
  for (int o=32;o>0;o>>=1) v = fmaxf(v,__shfl_xor(v,o,64));
  if ((threadIdx.x & 63) == 0) scr[threadIdx.x >> 6] = v;
  __syncthreads();
  float m = scr[0];
  #pragma unroll
  for (int i=1;i<8;i++) m = fmaxf(m, scr[i]);
  __syncthreads();
  return m;
}
__device__ __forceinline__ void sig_release(unsigned int* flag){
  __builtin_amdgcn_fence(__ATOMIC_RELEASE, "agent");
  __hip_atomic_fetch_add(flag, 1u, __ATOMIC_RELAXED, __HIP_MEMORY_SCOPE_AGENT);
}
__device__ __forceinline__ void spin_until(unsigned int* flag, unsigned int target){
  while (__hip_atomic_load(flag, __ATOMIC_RELAXED, __HIP_MEMORY_SCOPE_AGENT) < target)
    __builtin_amdgcn_s_sleep(2);
}
__device__ __forceinline__ void wait_acq1(unsigned int* f, unsigned int tgt){
  if (threadIdx.x==0){
    spin_until(f, tgt);
    __builtin_amdgcn_fence(__ATOMIC_ACQUIRE, "agent");
  }
  __syncthreads();
}
__device__ __forceinline__ void wait_acq2(unsigned int* f1, unsigned int t1,
                                          unsigned int* f2, unsigned int t2){
  if (threadIdx.x==0){
    spin_until(f1, t1);
    spin_until(f2, t2);
    __builtin_amdgcn_fence(__ATOMIC_ACQUIRE, "agent");
  }
  __syncthreads();
}

// ================= init =================
extern "C" __global__ void __launch_bounds__(256)
k_init(){
  size_t g = (size_t)blockIdx.x*256 + threadIdx.x;
  size_t stride = (size_t)gridDim.x*256;
  float* lk = &S_link[0][0][0];
  for (size_t i=g; i<(size_t)Bn*Nn*Nn; i+=stride) lk[i]=0.f;
  float* mm = &S_mem[0][0][0];
  for (size_t i=g; i<(size_t)Bn*Nn*WDn; i+=stride) mm[i]=0.f;
  float* rr = &S_rw[0][0][0];
  for (size_t i=g; i<(size_t)Bn*Rn*Nn; i+=stride) rr[i]=0.f;
  float* rd = &S_reads[0][0][0];
  for (size_t i=g; i<(size_t)Bn*Rn*WDn; i+=stride) rd[i]=0.f;
  for (size_t i=g; i<(size_t)2*Bn*Nn; i+=stride){
    S_ww[0][0][i]=0.f; S_prec[0][0][i]=0.f; S_usage[0][0][i]=0.f;
  }
  for (size_t i=g; i<(size_t)2*Bn*Hn; i+=stride){
    S_h[0][0][i]=0.f; S_c[0][0][i]=0.f;
  }
  if (blockIdx.x==0){
    if (threadIdx.x < Bn){
      g_ww[threadIdx.x]=0u; g_rc[threadIdx.x]=0u; g_ld[threadIdx.x]=0u; g_fb[threadIdx.x]=0u;
    }
    if (threadIdx.x == 0){ g_fin=0u; g_gate=0u; g_hh=0u; }
  }
}

// ================= shared-mem role layouts =================
struct ShG { float ctrl[Bn][65]; };
struct ShA {
  float hc[Hn];
  float itf[IFn];
  unsigned long long keys[Nn];
  float alloc[Nn];
  float sim[Nn];
  float rsim[Rn][Nn];
  float tile[64][65];
  float wkey[WDn];
  float rk[Rn][WDn];
  float er[WDn];
  float wv[WDn];
  float red[8];
  float knw, knr[Rn], betar[Rn];
};
struct ShL {
  float ww[Nn];
  float prec[Nn];
  float rw[Rn][Nn];
  float bwp4[4][Rn][Nn];
};
struct ShF {
  float fw[Rn][Nn];
  float bw[Rn][Nn];
  float rc[Rn][Nn];
  float modes[Rn][4];
  float part[8][Rn][WDn];
  float vin[512];
};
union ShU { ShA a; ShL l; ShF f; ShG g; };

// ========== the persistent kernel: 336 blocks x 512 ==========
// __launch_bounds__(512,4): hard VGPR cap 128 => >=2 blocks/CU by VGPR;
// LDS 45KB => 3 blocks/CU; guaranteed capacity min(512,768)=512 >= 336 grid.
// (R5's (512,2) allowed VGPR>128 -> 1 block/CU -> 256 < 336 -> deadlock.)
extern "C" __global__ void __launch_bounds__(512, 4)
k_all(const float* __restrict__ xin,
      const float* __restrict__ Wx, const float* __restrict__ Wh,
      const float* __restrict__ b_lstm,
      const float* __restrict__ W_if, const float* __restrict__ b_if,
      const float* __restrict__ W_out, const float* __restrict__ b_out,
      float* __restrict__ outp){
  __shared__ ShU sh;
  const int tid = threadIdx.x;
  const int lane = tid & 63, wvi = tid >> 6;
  const int bid = blockIdx.x;

  if (bid < 32){
    // ================= phaseA role =================
    const int b = bid;
    for (int t=0; t<Tn; ++t){
      const int cur = t&1, prev = cur^1;
      wait_acq2(&g_gate, 16u*(unsigned)(t+1), &g_fb[b], (unsigned)t);
      // LSTM combine from raw gates
      if (tid < Hn){
        int h = tid;
        float g0=S_gates[cur][b][h],     g1=S_gates[cur][b][Hn+h];
        float g2=S_gates[cur][b][2*Hn+h],g3=S_gates[cur][b][3*Hn+h];
        float cold = S_c[prev][b][h];
        float cn = sigm(g1)*cold + sigm(g0)*tanhf(g2);
        float hn = sigm(g3)*tanhf(cn);
        float hcv = clipv(hn);
        S_c[cur][b][h] = clipv(cn);
        S_h[cur][b][h] = hcv;
        sh.a.hc[h] = hcv;
      }
      __syncthreads();
      if (tid==0) sig_release(&g_hh);
      // itf = hc @ W_if + b_if
      if (tid < IFn){
        float acc = b_if[tid];
        for (int k=0;k<Hn;k+=8){
          float s = 0.f;
          #pragma unroll
          for (int u=0;u<8;u++) s += sh.a.hc[k+u]*W_if[(size_t)(k+u)*IFn + tid];
          acc += s;
        }
        sh.a.itf[tid] = acc;
        S_itf[b][tid] = acc;
      }
      __syncthreads();
      if (tid < WDn){
        sh.a.wkey[tid] = sh.a.itf[OFF_WKEY+tid];
        sh.a.er[tid]   = sigm(sh.a.itf[OFF_ERASE+tid]);
        sh.a.wv[tid]   = sh.a.itf[OFF_WVEC+tid];
      } else if (tid < WDn + Rn*WDn){
        int k2 = tid - WDn;
        sh.a.rk[k2>>6][k2&63] = sh.a.itf[OFF_RKEY + k2];
      }
      // usage update + stable-sort key
      {
        float fg0=sigm(sh.a.itf[OFF_FREE+0]), fg1=sigm(sh.a.itf[OFF_FREE+1]);
        float fg2=sigm(sh.a.itf[OFF_FREE+2]), fg3=sigm(sh.a.itf[OFF_FREE+3]);
        int n = tid;
        float uu = S_usage[prev][b][n], wwp = S_ww[prev][b][n];
        float u = uu + (1.f-uu)*wwp;
        float psi = (1.f - fg0*S_rw[b][0][n])*(1.f - fg1*S_rw[b][1][n])
                  * (1.f - fg2*S_rw[b][2][n])*(1.f - fg3*S_rw[b][3][n]);
        float un = u*psi;
        S_usage[cur][b][n] = un;
        float v = EPSV + (1.f-EPSV)*un;
        sh.a.keys[n] = ((unsigned long long)__float_as_uint(v) << 32) | (unsigned)n;
      }
      __syncthreads();
      // key norms
      if (wvi==0){
        float kv = sh.a.wkey[lane];
        float s2 = wredsum(kv*kv);
        if (lane==0) sh.a.knw = sqrtf(s2);
      } else if (wvi<=4){
        int r = wvi-1;
        float kv = sh.a.rk[r][lane];
        float s2 = wredsum(kv*kv);
        if (lane==0) sh.a.knr[r] = sqrtf(s2);
      } else if (wvi==5 && lane<4){
        sh.a.betar[lane] = oneplusf(sh.a.itf[OFF_RSTR+lane]);
      }
      // sort-free allocation
      {
        unsigned long long myk = sh.a.keys[tid];
        float prod = 1.f;
        for (int j=0;j<Nn;j+=8){
          #pragma unroll
          for (int u=0;u<8;u++){
            unsigned long long kj = sh.a.keys[j+u];
            float uj = __uint_as_float((unsigned)(kj>>32));
            prod *= (kj < myk) ? uj : 1.f;
          }
        }
        float myu = __uint_as_float((unsigned)(myk>>32));
        sh.a.alloc[tid] = (1.f - myu)*prod;
      }
      __syncthreads();
      // write-content sims over OLD mem
      float betaw = oneplusf(sh.a.itf[OFF_WSTR]);
      for (int tile=0;tile<8;tile++){
        #pragma unroll
        for (int u=0;u<8;u++){
          int e = u*512 + tid;
          int nn = e>>6, w = e&63;
          sh.a.tile[nn][w] = S_mem[b][tile*64+nn][w];
        }
        __syncthreads();
        {
          int nn = tid>>3, qq = tid&7;
          float d=0.f, nrm=0.f;
          #pragma unroll
          for (int i=0;i<8;i++){
            int w = qq*8+i;
            float m = sh.a.tile[nn][w];
            d += m*sh.a.wkey[w]; nrm += m*m;
          }
          #pragma unroll
          for (int o=1;o<8;o<<=1){ d += __shfl_xor(d,o,64); nrm += __shfl_xor(nrm,o,64); }
          if (qq==0){
            int n = tile*64+nn;
            sh.a.sim[n] = betaw * d / (sh.a.knw*sqrtf(nrm) + EPSV);
          }
        }
        __syncthreads();
      }
      // softmax -> wc ; ww ; sumww
      {
        float v = sh.a.sim[tid];
        float mx = bredmax(v, sh.a.red);
        float e = expf(v - mx);
        float ssum = bredsum(e, sh.a.red);
        float wc = e/ssum;
        float ag = sigm(sh.a.itf[OFF_AG]);
        float wg = sigm(sh.a.itf[OFF_WG]);
        float wwv = wg*(ag*sh.a.alloc[tid] + (1.f-ag)*wc);
        S_ww[cur][b][tid] = wwv;
        float wsum = bredsum(wwv, sh.a.red);
        if (tid==0) S_sumww[b] = wsum;
        sh.a.alloc[tid] = wwv;     // alloc now holds ww
      }
      __syncthreads();
      if (tid==0) sig_release(&g_ww[b]);
      // mem erase/write + read-content sims on NEW mem
      for (int tile=0;tile<8;tile++){
        #pragma unroll
        for (int u=0;u<8;u++){
          int e = u*512 + tid;
          int nn = e>>6, w = e&63;
          int n = tile*64+nn;
          float m = S_mem[b][n][w];
          float wwn = sh.a.alloc[n];
          m = m*(1.f - wwn*sh.a.er[w]) + wwn*sh.a.wv[w];
          S_mem[b][n][w] = m;
          sh.a.tile[nn][w] = m;
        }
        __syncthreads();
        {
          int nn = tid>>3, qq = tid&7;
          float a0=0.f,a1=0.f,a2=0.f,a3=0.f,nrm=0.f;
          #pragma unroll
          for (int i=0;i<8;i++){
            int w = qq*8+i;
            float m = sh.a.tile[nn][w];
            a0 += m*sh.a.rk[0][w]; a1 += m*sh.a.rk[1][w];
            a2 += m*sh.a.rk[2][w]; a3 += m*sh.a.rk[3][w];
            nrm += m*m;
          }
          #pragma unroll
          for (int o=1;o<8;o<<=1){
            a0 += __shfl_xor(a0,o,64); a1 += __shfl_xor(a1,o,64);
            a2 += __shfl_xor(a2,o,64); a3 += __shfl_xor(a3,o,64);
            nrm += __shfl_xor(nrm,o,64);
          }
          if (qq==0){
            int n = tile*64+nn;
            float mn = sqrtf(nrm);
            sh.a.rsim[0][n] = sh.a.betar[0]*a0/(sh.a.knr[0]*mn + EPSV);
            sh.a.rsim[1][n] = sh.a.betar[1]*a1/(sh.a.knr[1]*mn + EPSV);
            sh.a.rsim[2][n] = sh.a.betar[2]*a2/(sh.a.knr[2]*mn + EPSV);
            sh.a.rsim[3][n] = sh.a.betar[3]*a3/(sh.a.knr[3]*mn + EPSV);
          }
        }
        __syncthreads();
      }
      // rc softmax per head
      for (int r=0;r<Rn;r++){
        float v = sh.a.rsim[r][tid];
        float mx = bredmax(v, sh.a.red);
        float e = expf(v - mx);
        float ssum = bredsum(e, sh.a.red);
        S_rc[b][r][tid] = e/ssum;
      }
      __syncthreads();
      if (tid==0) sig_release(&g_rc[b]);
    }

  } else if (bid < 288){
    // ================= link role =================
    const int idx = bid - 32;
    const int b = idx >> 3, ch = idx & 7;
    const int i0 = ch*64;
    for (int t=0; t<Tn; ++t){
      const int cur = t&1, prev = cur^1;
      wait_acq1(&g_ww[b], (unsigned)(t+1));
      sh.l.ww[tid]   = S_ww[cur][b][tid];
      sh.l.prec[tid] = S_prec[prev][b][tid];
      for (int k=tid;k<Rn*Nn;k+=512) ((float*)sh.l.rw)[k] = ((const float*)S_rw[b])[k];
      __syncthreads();
      float sumww = S_sumww[b];
      float wj[2][4], pj[2][4], rj[4][2][4];
      #pragma unroll
      for (int jjc=0;jjc<2;jjc++){
        float4 w4 = ((const float4*)sh.l.ww)[jjc*64+lane];
        float4 p4 = ((const float4*)sh.l.prec)[jjc*64+lane];
        wj[jjc][0]=w4.x; wj[jjc][1]=w4.y; wj[jjc][2]=w4.z; wj[jjc][3]=w4.w;
        pj[jjc][0]=p4.x; pj[jjc][1]=p4.y; pj[jjc][2]=p4.z; pj[jjc][3]=p4.w;
        #pragma unroll
        for (int r=0;r<4;r++){
          float4 r4 = ((const float4*)sh.l.rw[r])[jjc*64+lane];
          rj[r][jjc][0]=r4.x; rj[r][jjc][1]=r4.y; rj[r][jjc][2]=r4.z; rj[r][jjc][3]=r4.w;
        }
      }
      float bwa[4][2][4];
      #pragma unroll
      for (int r=0;r<4;r++)
        #pragma unroll
        for (int jjc=0;jjc<2;jjc++)
          #pragma unroll
          for (int s=0;s<4;s++) bwa[r][jjc][s]=0.f;
      for (int rr=0;rr<8;rr++){
        const int i = i0 + wvi*8 + rr;
        float wi = sh.l.ww[i];
        float ci = 1.f - wi;
        float ri[4] = {sh.l.rw[0][i], sh.l.rw[1][i], sh.l.rw[2][i], sh.l.rw[3][i]};
        float f[4] = {0.f,0.f,0.f,0.f};
        float4* lrow4 = (float4*)(&S_link[b][i][0]);
        #pragma unroll
        for (int jjc=0;jjc<2;jjc++){
          float4 L4 = lrow4[jjc*64+lane];
          float Ls[4] = {L4.x, L4.y, L4.z, L4.w};
          #pragma unroll
          for (int s=0;s<4;s++){
            float Ln = (ci - wj[jjc][s])*Ls[s] + wi*pj[jjc][s];
            int j = jjc*256 + lane*4 + s;
            Ln = (j==i) ? 0.f : Ln;
            Ls[s] = Ln;
            #pragma unroll
            for (int r=0;r<4;r++){
              f[r] += Ln*rj[r][jjc][s];
              bwa[r][jjc][s] += Ln*ri[r];
            }
          }
          float4 Lo; Lo.x=Ls[0]; Lo.y=Ls[1]; Lo.z=Ls[2]; Lo.w=Ls[3];
          lrow4[jjc*64+lane] = Lo;
        }
        #pragma unroll
        for (int r=0;r<4;r++){
          float fr = wredsum(f[r]);
          if (lane==0) S_fw[b][r][i] = fr;
        }
      }
      if (wvi < 4){
        #pragma unroll
        for (int r=0;r<4;r++)
          #pragma unroll
          for (int jjc=0;jjc<2;jjc++){
            float4 v4; v4.x=bwa[r][jjc][0]; v4.y=bwa[r][jjc][1]; v4.z=bwa[r][jjc][2]; v4.w=bwa[r][jjc][3];
            ((float4*)sh.l.bwp4[wvi][r])[jjc*64+lane] = v4;
          }
      }
      __syncthreads();
      if (wvi >= 4){
        int v = wvi-4;
        #pragma unroll
        for (int r=0;r<4;r++)
          #pragma unroll
          for (int jjc=0;jjc<2;jjc++){
            float4 v4 = ((float4*)sh.l.bwp4[v][r])[jjc*64+lane];
            v4.x+=bwa[r][jjc][0]; v4.y+=bwa[r][jjc][1]; v4.z+=bwa[r][jjc][2]; v4.w+=bwa[r][jjc][3];
            ((float4*)sh.l.bwp4[v][r])[jjc*64+lane] = v4;
          }
      }
      __syncthreads();
      for (int k=tid;k<Rn*Nn;k+=512){
        float s = ((float*)sh.l.bwp4[0])[k] + ((float*)sh.l.bwp4[1])[k]
                + ((float*)sh.l.bwp4[2])[k] + ((float*)sh.l.bwp4[3])[k];
        S_bwp[b][ch][k] = s;
      }
      if (tid < 64){
        int j = i0 + tid;
        S_prec[cur][b][j] = (1.f - sumww)*sh.l.prec[j] + sh.l.ww[j];
      }
      __syncthreads();
      if (tid==0) sig_release(&g_ld[b]);
    }

  } else if (bid < 320){
    // ================= finalize role =================
    const int b = bid - 288;
    for (int t=0; t<Tn; ++t){
      const int cur = t&1;
      wait_acq2(&g_ld[b], 8u*(unsigned)(t+1), &g_rc[b], (unsigned)(t+1));
      for (int k=tid;k<Rn*Nn;k+=512){
        ((float*)sh.f.fw)[k] = ((const float*)S_fw[b])[k];
        float sbw = 0.f;
        #pragma unroll
        for (int ch=0;ch<8;ch++) sbw += S_bwp[b][ch][k];
        ((float*)sh.f.bw)[k] = sbw;
        ((float*)sh.f.rc)[k] = ((const float*)S_rc[b])[k];
      }
      if (tid < 4){
        int r = tid;
        float m0 = S_itf[b][OFF_MODES + r*3 + 0];
        float m1 = S_itf[b][OFF_MODES + r*3 + 1];
        float m2 = S_itf[b][OFF_MODES + r*3 + 2];
        float mx = fmaxf(m0,fmaxf(m1,m2));
        float e0=expf(m0-mx), e1=expf(m1-mx), e2=expf(m2-mx);
        float si = e0+e1+e2;
        sh.f.modes[r][0]=e0/si; sh.f.modes[r][1]=e1/si; sh.f.modes[r][2]=e2/si;
      }
      __syncthreads();
      for (int k=tid;k<Rn*Nn;k+=512){
        int r = k>>9, n = k&511;
        float v = sh.f.modes[r][2]*sh.f.rc[r][n] + sh.f.modes[r][1]*sh.f.fw[r][n]
                + sh.f.modes[r][0]*sh.f.bw[r][n];
        sh.f.rc[r][n] = v;
        S_rw[b][r][n] = v;
      }
      __syncthreads();
      {
        float a0=0.f,a1=0.f,a2=0.f,a3=0.f;
        #pragma unroll 4
        for (int nn=0;nn<64;nn++){
          int n = wvi*64+nn;
          float m = S_mem[b][n][lane];
          a0 += sh.f.rc[0][n]*m; a1 += sh.f.rc[1][n]*m;
          a2 += sh.f.rc[2][n]*m; a3 += sh.f.rc[3][n]*m;
        }
        sh.f.part[wvi][0][lane]=a0; sh.f.part[wvi][1][lane]=a1;
        sh.f.part[wvi][2][lane]=a2; sh.f.part[wvi][3][lane]=a3;
      }
      __syncthreads();
      if (tid < 256){
        int r = tid>>6, w = tid&63;
        float sv = 0.f;
        #pragma unroll
        for (int v=0;v<8;v++) sv += sh.f.part[v][r][w];
        S_reads[b][r][w] = sv;
        sh.f.vin[256+tid] = sv;
        sh.f.vin[tid] = S_h[cur][b][tid];
      }
      __syncthreads();
      {
        int qq = tid>>6, o = tid&63;
        float sacc = 0.f;
        for (int k2=qq*64;k2<qq*64+64;k2+=8){
          #pragma unroll
          for (int u=0;u<8;u++) sacc += sh.f.vin[k2+u]*W_out[(size_t)(k2+u)*OUTn + o];
        }
        sh.f.part[qq][0][o] = sacc;
      }
      __syncthreads();
      if (tid < 64){
        float sv = b_out[tid];
        #pragma unroll
        for (int qq=0;qq<8;qq++) sv += sh.f.part[qq][0][tid];
        outp[((size_t)t*Bn + b)*OUTn + tid] = clipv(sv);
      }
      __syncthreads();
      if (tid==0){
        __builtin_amdgcn_fence(__ATOMIC_RELEASE, "agent");
        __hip_atomic_fetch_add(&g_fb[b], 1u, __ATOMIC_RELAXED, __HIP_MEMORY_SCOPE_AGENT);
        __hip_atomic_fetch_add(&g_fin, 1u, __ATOMIC_RELAXED, __HIP_MEMORY_SCOPE_AGENT);
      }
    }

  } else {
    // ================= gates role: compute gates(t) during step t-1 =======
    const int jt = bid - 320;
    const int j = jt*64 + lane;
    const int b0 = wvi*4;
    for (int t=0; t<Tn; ++t){
      const int hp = (t+1)&1;     // slot of h(t-1)
      float bias = b_lstm[j];
      float a0=bias, a1=bias, a2=bias, a3=bias;
      // --- part 1: x(t) and h(t-1) contributions ---
      wait_acq1(&g_hh, 32u*(unsigned)t);
      for (int c=0;c<5;++c){          // c=0: x ; c=1..4: h chunks
        #pragma unroll
        for (int u=0;u<4;u++){
          int e = u*512 + tid;
          int b2 = e >> 6, kk = e & 63;
          float v;
          if (c==0) v = xin[((size_t)t*Bn + b2)*INn + kk];
          else      v = S_h[hp][b2][(c-1)*64 + kk];
          sh.g.ctrl[b2][kk] = v;
        }
        __syncthreads();
        const float* wb = (c==0) ? (Wx + (size_t)0*G4H + j)
                                 : (Wh + (size_t)((c-1)*64)*G4H + j);
        #pragma unroll
        for (int kk=0;kk<64;kk++){
          float wv = wb[(size_t)kk*G4H];
          a0 += sh.g.ctrl[b0+0][kk]*wv;
          a1 += sh.g.ctrl[b0+1][kk]*wv;
          a2 += sh.g.ctrl[b0+2][kk]*wv;
          a3 += sh.g.ctrl[b0+3][kk]*wv;
        }
        __syncthreads();
      }
      // --- part 2: reads(t-1) contributions ---
      wait_acq1(&g_fin, 32u*(unsigned)t);
      for (int c=0;c<4;++c){
        #pragma unroll
        for (int u=0;u<4;u++){
          int e = u*512 + tid;
          int b2 = e >> 6, kk = e & 63;
          sh.g.ctrl[b2][kk] = ((const float*)S_reads[b2])[c*64 + kk];
        }
        __syncthreads();
        const float* wb = Wx + (size_t)(INn + c*64)*G4H + j;
        #pragma unroll
        for (int kk=0;kk<64;kk++){
          float wv = wb[(size_t)kk*G4H];
          a0 += sh.g.ctrl[b0+0][kk]*wv;
          a1 += sh.g.ctrl[b0+1][kk]*wv;
          a2 += sh.g.ctrl[b0+2][kk]*wv;
          a3 += sh.g.ctrl[b0+3][kk]*wv;
        }
        __syncthreads();
      }
      const int gs = t&1;
      S_gates[gs][b0+0][j]=a0;
      S_gates[gs][b0+1][j]=a1;
      S_gates[gs][b0+2][j]=a2;
      S_gates[gs][b0+3][j]=a3;
      __syncthreads();
      if (tid==0) sig_release(&g_gate);
    }
  }
}

extern "C" void kernel_launch(void* const* d_in, const int* in_sizes, int n_in,
                              void* d_out, int out_size, void* d_ws, size_t ws_size,
                              hipStream_t stream){
  (void)in_sizes; (void)n_in; (void)d_ws; (void)ws_size; (void)out_size;
  const float* xin = (const float*)d_in[0];
  const float* Wx  = (const float*)d_in[1];
  const float* Wh  = (const float*)d_in[2];
  const float* bl  = (const float*)d_in[3];
  const float* Wif = (const float*)d_in[4];
  const float* bif = (const float*)d_in[5];
  const float* Wo  = (const float*)d_in[6];
  const float* bo  = (const float*)d_in[7];
  hipLaunchKernelGGL(k_init, dim3(1024), dim3(256), 0, stream);
  hipLaunchKernelGGL(k_all, dim3(336), dim3(512), 0, stream,
                     xin, Wx, Wh, bl, Wif, bif, Wo, bo, (float*)d_out);
}

// Round 7
// 6347.333 us; speedup vs baseline: 2.3630x; 2.3630x over previous
//
#include <hip/hip_runtime.h>
#include <math.h>

#define Tn 64
#define Bn 32
#define INn 64
#define Nn 512
#define WDn 64
#define Rn 4
#define Hn 256
#define G4H 1024
#define OUTn 64
#define IFn 471
#define CLIPV 20.0f
#define EPSV 1e-6f

#define OFF_RKEY 0
#define OFF_RSTR 256
#define OFF_WKEY 260
#define OFF_WSTR 324
#define OFF_ERASE 325
#define OFF_WVEC 389
#define OFF_FREE 453
#define OFF_AG 457
#define OFF_WG 458
#define OFF_MODES 459

// ---------------- persistent device state ----------------
__device__ float S_h[2][Bn][Hn];          // h(t) in slot t&1
__device__ float S_c[2][Bn][Hn];
__device__ float S_gates[2][Bn][G4H];     // raw gates(t) in slot t&1
__device__ float S_mem[Bn][Nn][WDn];
__device__ float S_rw[Bn][Rn][Nn];        // rw(t), written by fin(t)
__device__ float S_ww[2][Bn][Nn];
__device__ float S_link[Bn][Nn][Nn];
__device__ float S_prec[2][Bn][Nn];
__device__ float S_usage[2][Bn][Nn];
__device__ float S_reads[Bn][Rn][WDn];
__device__ float S_itf[Bn][IFn];
__device__ float S_fw[Bn][Rn][Nn];
__device__ float S_bwp[Bn][8][Rn*Nn];
__device__ float S_sumww[Bn];
// monotonic flags, padded to 64B lines
__device__ unsigned int g_hh[16];         // 32*(t+1) when all h(t) written
__device__ unsigned int g_ww[Bn][16];     // t+1 when ww(t) ready (per batch)
__device__ unsigned int g_ld[Bn][16];     // 8*(t+1) when link(t) done (per batch)
__device__ unsigned int g_fin[16];        // 32*(t+1) when all fin(t) done

// ---------------- helpers ----------------
__device__ __forceinline__ float sigm(float x){ return 1.f/(1.f+expf(-x)); }
__device__ __forceinline__ float clipv(float x){ return fminf(fmaxf(x,-CLIPV),CLIPV); }
__device__ __forceinline__ float oneplusf(float x){
  float sp = (x > 0.f) ? (x + log1pf(expf(-x))) : log1pf(expf(x));
  return 1.f + sp;
}
__device__ __forceinline__ float wredsum(float v){
  #pragma unroll
  for (int o=32;o>0;o>>=1) v += __shfl_xor(v,o,64);
  return v;
}
__device__ __forceinline__ float bredsum(float v, volatile float* scr){
  v = wredsum(v);
  if ((threadIdx.x & 63) == 0) scr[threadIdx.x >> 6] = v;
  __syncthreads();
  float s = scr[0];
  #pragma unroll
  for (int i=1;i<8;i++) s += scr[i];
  __syncthreads();
  return s;
}
__device__ __forceinline__ float bredmax(float v, volatile float* scr){
  #pragma unroll
  for (int o=32;o>0;o>>=1) v = fmaxf(v,__shfl_xor(v,o,64));
  if ((threadIdx.x & 63) == 0) scr[threadIdx.x >> 6] = v;
  __syncthreads();
  float m = scr[0];
  #pragma unroll
  for (int i=1;i<8;i++) m = fmaxf(m, scr[i]);
  __syncthreads();
  return m;
}
__device__ __forceinline__ void sig_release(unsigned int* flag){
  __builtin_amdgcn_fence(__ATOMIC_RELEASE, "agent");
  __hip_atomic_fetch_add(flag, 1u, __ATOMIC_RELAXED, __HIP_MEMORY_SCOPE_AGENT);
}
__device__ __forceinline__ void spin_until(unsigned int* flag, unsigned int target){
  while (__hip_atomic_load(flag, __ATOMIC_RELAXED, __HIP_MEMORY_SCOPE_AGENT) < target)
    __builtin_amdgcn_s_sleep(4);
}
__device__ __forceinline__ void wait_acq1(unsigned int* f, unsigned int tgt){
  if (threadIdx.x==0){
    spin_until(f, tgt);
    __builtin_amdgcn_fence(__ATOMIC_ACQUIRE, "agent");
  }
  __syncthreads();
}

// ================= init =================
extern "C" __global__ void __launch_bounds__(256)
k_init(){
  size_t g = (size_t)blockIdx.x*256 + threadIdx.x;
  size_t stride = (size_t)gridDim.x*256;
  float* lk = &S_link[0][0][0];
  for (size_t i=g; i<(size_t)Bn*Nn*Nn; i+=stride) lk[i]=0.f;
  float* mm = &S_mem[0][0][0];
  for (size_t i=g; i<(size_t)Bn*Nn*WDn; i+=stride) mm[i]=0.f;
  float* rr = &S_rw[0][0][0];
  for (size_t i=g; i<(size_t)Bn*Rn*Nn; i+=stride) rr[i]=0.f;
  float* rd = &S_reads[0][0][0];
  for (size_t i=g; i<(size_t)Bn*Rn*WDn; i+=stride) rd[i]=0.f;
  for (size_t i=g; i<(size_t)2*Bn*Nn; i+=stride){
    S_ww[0][0][i]=0.f; S_prec[0][0][i]=0.f; S_usage[0][0][i]=0.f;
  }
  for (size_t i=g; i<(size_t)2*Bn*Hn; i+=stride){
    S_h[0][0][i]=0.f; S_c[0][0][i]=0.f;
  }
  if (blockIdx.x==0){
    for (int i=threadIdx.x; i<16; i+=256){ g_hh[i]=0u; g_fin[i]=0u; }
    for (int i=threadIdx.x; i<Bn*16; i+=256){
      ((unsigned int*)g_ww)[i]=0u; ((unsigned int*)g_ld)[i]=0u;
    }
  }
}

// ================= shared-mem role layouts =================
struct ShG { float ctrl[Bn][65]; };
struct ShA {
  float hc[Hn];
  float itf[IFn];
  unsigned long long keys[Nn];
  float alloc[Nn];
  float sim[Nn];
  float tile[64][65];
  float wkey[WDn];
  float red[8];
  float knw;
};
struct ShL {
  float ww[Nn];
  float prec[Nn];
  float rw[Rn][Nn];
  float bwp4[4][Rn][Nn];
};
struct ShF {
  float er[WDn];
  float wv[WDn];
  float rk[Rn][WDn];
  float betar[Rn];
  float knr[Rn];
  float modes[Rn][4];
  float ww[Nn];
  float tile[64][65];
  float rsim[Rn][Nn];     // rc sims -> rc -> rw
  float fw[Rn][Nn];
  float bw[Rn][Nn];
  float part[8][Rn][WDn];
  float vin[512];
  float red[8];
};
union ShU { ShA a; ShL l; ShF f; ShG g; };

// ================= gates prologue: gates(0), all 9 chunks =================
extern "C" __global__ void __launch_bounds__(512)
k_gates_pro(const float* __restrict__ xin, const float* __restrict__ Wx,
            const float* __restrict__ Wh, const float* __restrict__ b_lstm){
  __shared__ ShG sg;
  const int tid = threadIdx.x, lane = tid & 63, wvi = tid >> 6;
  const int j = blockIdx.x*64 + lane;
  const int b0 = wvi*4;
  float bias = b_lstm[j];
  float a0=bias, a1=bias, a2=bias, a3=bias;
  for (int c=0;c<9;++c){
    #pragma unroll
    for (int u=0;u<4;u++){
      int e = u*512 + tid;
      int b2 = e >> 6, kk = e & 63;
      float v;
      if (c==0)       v = xin[(size_t)b2*INn + kk];     // t=0
      else if (c<5)   v = 0.f;                          // reads(-1)=0
      else            v = 0.f;                          // h(-1)=0
      sg.ctrl[b2][kk] = v;
    }
    __syncthreads();
    const float* wb = (c<5) ? (Wx + (size_t)(c*64)*G4H + j)
                            : (Wh + (size_t)((c-5)*64)*G4H + j);
    #pragma unroll
    for (int kk=0;kk<64;kk++){
      float wv = wb[(size_t)kk*G4H];
      a0 += sg.ctrl[b0+0][kk]*wv;
      a1 += sg.ctrl[b0+1][kk]*wv;
      a2 += sg.ctrl[b0+2][kk]*wv;
      a3 += sg.ctrl[b0+3][kk]*wv;
    }
    __syncthreads();
  }
  S_gates[0][b0+0][j]=a0;
  S_gates[0][b0+1][j]=a1;
  S_gates[0][b0+2][j]=a2;
  S_gates[0][b0+3][j]=a3;
}

// ================= per-step kernel: 336 blocks x 512 =================
extern "C" __global__ void __launch_bounds__(512, 4)
k_step(int t, const float* __restrict__ xin,
       const float* __restrict__ Wx, const float* __restrict__ Wh,
       const float* __restrict__ b_lstm,
       const float* __restrict__ W_if, const float* __restrict__ b_if,
       const float* __restrict__ W_out, const float* __restrict__ b_out,
       float* __restrict__ outp){
  __shared__ ShU sh;
  const int tid = threadIdx.x;
  const int lane = tid & 63, wvi = tid >> 6;
  const int bid = blockIdx.x;
  const int cur = t&1, prev = cur^1;

  if (bid < 32){
    // ================= phaseA: LSTM -> itf -> alloc/wc -> ww =================
    const int b = bid;
    // LSTM combine from raw gates (written last dispatch / prologue)
    if (tid < Hn){
      int h = tid;
      float g0=S_gates[cur][b][h],     g1=S_gates[cur][b][Hn+h];
      float g2=S_gates[cur][b][2*Hn+h],g3=S_gates[cur][b][3*Hn+h];
      float cold = S_c[prev][b][h];
      float cn = sigm(g1)*cold + sigm(g0)*tanhf(g2);
      float hn = sigm(g3)*tanhf(cn);
      float hcv = clipv(hn);
      S_c[cur][b][h] = clipv(cn);
      S_h[cur][b][h] = hcv;
      sh.a.hc[h] = hcv;
    }
    __syncthreads();
    if (tid==0) sig_release(&g_hh[0]);    // gates part1 may start
    // itf = hc @ W_if + b_if (unroll 16)
    if (tid < IFn){
      float acc = b_if[tid];
      for (int k=0;k<Hn;k+=16){
        float s = 0.f;
        #pragma unroll
        for (int u=0;u<16;u++) s += sh.a.hc[k+u]*W_if[(size_t)(k+u)*IFn + tid];
        acc += s;
      }
      sh.a.itf[tid] = acc;
      S_itf[b][tid] = acc;
    }
    __syncthreads();
    if (tid < WDn) sh.a.wkey[tid] = sh.a.itf[OFF_WKEY+tid];
    // usage update + stable-sort key
    {
      float fg0=sigm(sh.a.itf[OFF_FREE+0]), fg1=sigm(sh.a.itf[OFF_FREE+1]);
      float fg2=sigm(sh.a.itf[OFF_FREE+2]), fg3=sigm(sh.a.itf[OFF_FREE+3]);
      int n = tid;
      float uu = S_usage[prev][b][n], wwp = S_ww[prev][b][n];
      float u = uu + (1.f-uu)*wwp;
      float psi = (1.f - fg0*S_rw[b][0][n])*(1.f - fg1*S_rw[b][1][n])
                * (1.f - fg2*S_rw[b][2][n])*(1.f - fg3*S_rw[b][3][n]);
      float un = u*psi;
      S_usage[cur][b][n] = un;
      float v = EPSV + (1.f-EPSV)*un;
      sh.a.keys[n] = ((unsigned long long)__float_as_uint(v) << 32) | (unsigned)n;
    }
    __syncthreads();
    // write-key norm (wave 0) + sort-free allocation (all threads)
    if (wvi==0){
      float kv = sh.a.wkey[lane];
      float s2 = wredsum(kv*kv);
      if (lane==0) sh.a.knw = sqrtf(s2);
    }
    {
      unsigned long long myk = sh.a.keys[tid];
      float prod = 1.f;
      for (int j=0;j<Nn;j+=8){
        #pragma unroll
        for (int u=0;u<8;u++){
          unsigned long long kj = sh.a.keys[j+u];
          float uj = __uint_as_float((unsigned)(kj>>32));
          prod *= (kj < myk) ? uj : 1.f;
        }
      }
      float myu = __uint_as_float((unsigned)(myk>>32));
      sh.a.alloc[tid] = (1.f - myu)*prod;
    }
    __syncthreads();
    // write-content sims over OLD mem
    float betaw = oneplusf(sh.a.itf[OFF_WSTR]);
    for (int tile=0;tile<8;tile++){
      #pragma unroll
      for (int u=0;u<8;u++){
        int e = u*512 + tid;
        int nn = e>>6, w = e&63;
        sh.a.tile[nn][w] = S_mem[b][tile*64+nn][w];
      }
      __syncthreads();
      {
        int nn = tid>>3, qq = tid&7;
        float d=0.f, nrm=0.f;
        #pragma unroll
        for (int i=0;i<8;i++){
          int w = qq*8+i;
          float m = sh.a.tile[nn][w];
          d += m*sh.a.wkey[w]; nrm += m*m;
        }
        #pragma unroll
        for (int o=1;o<8;o<<=1){ d += __shfl_xor(d,o,64); nrm += __shfl_xor(nrm,o,64); }
        if (qq==0){
          int n = tile*64+nn;
          sh.a.sim[n] = betaw * d / (sh.a.knw*sqrtf(nrm) + EPSV);
        }
      }
      __syncthreads();
    }
    // softmax -> wc ; ww ; sumww ; release
    {
      float v = sh.a.sim[tid];
      float mx = bredmax(v, sh.a.red);
      float e = expf(v - mx);
      float ssum = bredsum(e, sh.a.red);
      float wc = e/ssum;
      float ag = sigm(sh.a.itf[OFF_AG]);
      float wg = sigm(sh.a.itf[OFF_WG]);
      float wwv = wg*(ag*sh.a.alloc[tid] + (1.f-ag)*wc);
      S_ww[cur][b][tid] = wwv;
      float wsum = bredsum(wwv, sh.a.red);
      if (tid==0) S_sumww[b] = wsum;
    }
    __syncthreads();
    if (tid==0) sig_release(&g_ww[b][0]);

  } else if (bid < 288){
    // ================= link =================
    const int idx = bid - 32;
    const int b = idx >> 3, ch = idx & 7;
    const int i0 = ch*64;
    wait_acq1(&g_ww[b][0], (unsigned)(t+1));
    sh.l.ww[tid]   = S_ww[cur][b][tid];
    sh.l.prec[tid] = S_prec[prev][b][tid];
    for (int k=tid;k<Rn*Nn;k+=512) ((float*)sh.l.rw)[k] = ((const float*)S_rw[b])[k];
    __syncthreads();
    float sumww = S_sumww[b];
    float wj[2][4], pj[2][4], rj[4][2][4];
    #pragma unroll
    for (int jjc=0;jjc<2;jjc++){
      float4 w4 = ((const float4*)sh.l.ww)[jjc*64+lane];
      float4 p4 = ((const float4*)sh.l.prec)[jjc*64+lane];
      wj[jjc][0]=w4.x; wj[jjc][1]=w4.y; wj[jjc][2]=w4.z; wj[jjc][3]=w4.w;
      pj[jjc][0]=p4.x; pj[jjc][1]=p4.y; pj[jjc][2]=p4.z; pj[jjc][3]=p4.w;
      #pragma unroll
      for (int r=0;r<4;r++){
        float4 r4 = ((const float4*)sh.l.rw[r])[jjc*64+lane];
        rj[r][jjc][0]=r4.x; rj[r][jjc][1]=r4.y; rj[r][jjc][2]=r4.z; rj[r][jjc][3]=r4.w;
      }
    }
    float bwa[4][2][4];
    #pragma unroll
    for (int r=0;r<4;r++)
      #pragma unroll
      for (int jjc=0;jjc<2;jjc++)
        #pragma unroll
        for (int s=0;s<4;s++) bwa[r][jjc][s]=0.f;
    for (int rr=0;rr<8;rr++){
      const int i = i0 + wvi*8 + rr;
      float wi = sh.l.ww[i];
      float ci = 1.f - wi;
      float ri[4] = {sh.l.rw[0][i], sh.l.rw[1][i], sh.l.rw[2][i], sh.l.rw[3][i]};
      float f[4] = {0.f,0.f,0.f,0.f};
      float4* lrow4 = (float4*)(&S_link[b][i][0]);
      #pragma unroll
      for (int jjc=0;jjc<2;jjc++){
        float4 L4 = lrow4[jjc*64+lane];
        float Ls[4] = {L4.x, L4.y, L4.z, L4.w};
        #pragma unroll
        for (int s=0;s<4;s++){
          float Ln = (ci - wj[jjc][s])*Ls[s] + wi*pj[jjc][s];
          int j = jjc*256 + lane*4 + s;
          Ln = (j==i) ? 0.f : Ln;
          Ls[s] = Ln;
          #pragma unroll
          for (int r=0;r<4;r++){
            f[r] += Ln*rj[r][jjc][s];
            bwa[r][jjc][s] += Ln*ri[r];
          }
        }
        float4 Lo; Lo.x=Ls[0]; Lo.y=Ls[1]; Lo.z=Ls[2]; Lo.w=Ls[3];
        lrow4[jjc*64+lane] = Lo;
      }
      #pragma unroll
      for (int r=0;r<4;r++){
        float fr = wredsum(f[r]);
        if (lane==0) S_fw[b][r][i] = fr;
      }
    }
    if (wvi < 4){
      #pragma unroll
      for (int r=0;r<4;r++)
        #pragma unroll
        for (int jjc=0;jjc<2;jjc++){
          float4 v4; v4.x=bwa[r][jjc][0]; v4.y=bwa[r][jjc][1]; v4.z=bwa[r][jjc][2]; v4.w=bwa[r][jjc][3];
          ((float4*)sh.l.bwp4[wvi][r])[jjc*64+lane] = v4;
        }
    }
    __syncthreads();
    if (wvi >= 4){
      int v = wvi-4;
      #pragma unroll
      for (int r=0;r<4;r++)
        #pragma unroll
        for (int jjc=0;jjc<2;jjc++){
          float4 v4 = ((float4*)sh.l.bwp4[v][r])[jjc*64+lane];
          v4.x+=bwa[r][jjc][0]; v4.y+=bwa[r][jjc][1]; v4.z+=bwa[r][jjc][2]; v4.w+=bwa[r][jjc][3];
          ((float4*)sh.l.bwp4[v][r])[jjc*64+lane] = v4;
        }
    }
    __syncthreads();
    for (int k=tid;k<Rn*Nn;k+=512){
      float s = ((float*)sh.l.bwp4[0])[k] + ((float*)sh.l.bwp4[1])[k]
              + ((float*)sh.l.bwp4[2])[k] + ((float*)sh.l.bwp4[3])[k];
      S_bwp[b][ch][k] = s;
    }
    if (tid < 64){
      int j = i0 + tid;
      S_prec[cur][b][j] = (1.f - sumww)*sh.l.prec[j] + sh.l.ww[j];
    }
    __syncthreads();
    if (tid==0) sig_release(&g_ld[b][0]);

  } else if (bid < 320){
    // ================= fin: mem update + rc (overlaps link) -> rw/reads/out =
    const int b = bid - 288;
    wait_acq1(&g_ww[b][0], (unsigned)(t+1));
    // staging from itf / ww
    if (tid < WDn){
      sh.f.er[tid] = sigm(S_itf[b][OFF_ERASE+tid]);
      sh.f.wv[tid] = S_itf[b][OFF_WVEC+tid];
    } else if (tid < WDn + Rn*WDn){
      int k2 = tid - WDn;
      sh.f.rk[k2>>6][k2&63] = S_itf[b][OFF_RKEY + k2];
    } else if (tid < WDn + Rn*WDn + Rn){
      int r = tid - (WDn+Rn*WDn);
      sh.f.betar[r] = oneplusf(S_itf[b][OFF_RSTR + r]);
    } else if (tid >= 384 && tid < 384+Rn){
      int r = tid - 384;
      float m0 = S_itf[b][OFF_MODES + r*3 + 0];
      float m1 = S_itf[b][OFF_MODES + r*3 + 1];
      float m2 = S_itf[b][OFF_MODES + r*3 + 2];
      float mx = fmaxf(m0,fmaxf(m1,m2));
      float e0=expf(m0-mx), e1=expf(m1-mx), e2=expf(m2-mx);
      float si = e0+e1+e2;
      sh.f.modes[r][0]=e0/si; sh.f.modes[r][1]=e1/si; sh.f.modes[r][2]=e2/si;
    }
    sh.f.ww[tid] = S_ww[cur][b][tid];
    __syncthreads();
    if (wvi < 4){
      float kv = sh.f.rk[wvi][lane];
      float s2 = wredsum(kv*kv);
      if (lane==0) sh.f.knr[wvi] = sqrtf(s2);
    }
    // mem erase/write + read-content sims (overlaps link role)
    for (int tile=0;tile<8;tile++){
      #pragma unroll
      for (int u=0;u<8;u++){
        int e = u*512 + tid;
        int nn = e>>6, w = e&63;
        int n = tile*64+nn;
        float m = S_mem[b][n][w];
        float wwn = sh.f.ww[n];
        m = m*(1.f - wwn*sh.f.er[w]) + wwn*sh.f.wv[w];
        S_mem[b][n][w] = m;
        sh.f.tile[nn][w] = m;
      }
      __syncthreads();
      {
        int nn = tid>>3, qq = tid&7;
        float a0=0.f,a1=0.f,a2=0.f,a3=0.f,nrm=0.f;
        #pragma unroll
        for (int i=0;i<8;i++){
          int w = qq*8+i;
          float m = sh.f.tile[nn][w];
          a0 += m*sh.f.rk[0][w]; a1 += m*sh.f.rk[1][w];
          a2 += m*sh.f.rk[2][w]; a3 += m*sh.f.rk[3][w];
          nrm += m*m;
        }
        #pragma unroll
        for (int o=1;o<8;o<<=1){
          a0 += __shfl_xor(a0,o,64); a1 += __shfl_xor(a1,o,64);
          a2 += __shfl_xor(a2,o,64); a3 += __shfl_xor(a3,o,64);
          nrm += __shfl_xor(nrm,o,64);
        }
        if (qq==0){
          int n = tile*64+nn;
          float mn = sqrtf(nrm);
          sh.f.rsim[0][n] = sh.f.betar[0]*a0/(sh.f.knr[0]*mn + EPSV);
          sh.f.rsim[1][n] = sh.f.betar[1]*a1/(sh.f.knr[1]*mn + EPSV);
          sh.f.rsim[2][n] = sh.f.betar[2]*a2/(sh.f.knr[2]*mn + EPSV);
          sh.f.rsim[3][n] = sh.f.betar[3]*a3/(sh.f.knr[3]*mn + EPSV);
        }
      }
      __syncthreads();
    }
    // rc softmax per head (in place)
    for (int r=0;r<Rn;r++){
      float v = sh.f.rsim[r][tid];
      float mx = bredmax(v, sh.f.red);
      float e = expf(v - mx);
      float ssum = bredsum(e, sh.f.red);
      sh.f.rsim[r][tid] = e/ssum;
    }
    __syncthreads();
    // wait for link, then combine rw
    wait_acq1(&g_ld[b][0], 8u*(unsigned)(t+1));
    for (int k=tid;k<Rn*Nn;k+=512){
      ((float*)sh.f.fw)[k] = ((const float*)S_fw[b])[k];
      float sbw = 0.f;
      #pragma unroll
      for (int ch=0;ch<8;ch++) sbw += S_bwp[b][ch][k];
      ((float*)sh.f.bw)[k] = sbw;
    }
    __syncthreads();
    for (int k=tid;k<Rn*Nn;k+=512){
      int r = k>>9, n = k&511;
      float v = sh.f.modes[r][2]*sh.f.rsim[r][n] + sh.f.modes[r][1]*sh.f.fw[r][n]
              + sh.f.modes[r][0]*sh.f.bw[r][n];
      sh.f.rsim[r][n] = v;
      S_rw[b][r][n] = v;
    }
    __syncthreads();
    // reads = rw @ mem  (mem is L2-hot from the update pass)
    {
      float a0=0.f,a1=0.f,a2=0.f,a3=0.f;
      #pragma unroll 4
      for (int nn=0;nn<64;nn++){
        int n = wvi*64+nn;
        float m = S_mem[b][n][lane];
        a0 += sh.f.rsim[0][n]*m; a1 += sh.f.rsim[1][n]*m;
        a2 += sh.f.rsim[2][n]*m; a3 += sh.f.rsim[3][n]*m;
      }
      sh.f.part[wvi][0][lane]=a0; sh.f.part[wvi][1][lane]=a1;
      sh.f.part[wvi][2][lane]=a2; sh.f.part[wvi][3][lane]=a3;
    }
    __syncthreads();
    if (tid < 256){
      int r = tid>>6, w = tid&63;
      float sv = 0.f;
      #pragma unroll
      for (int v=0;v<8;v++) sv += sh.f.part[v][r][w];
      S_reads[b][r][w] = sv;
      sh.f.vin[256+tid] = sv;
      sh.f.vin[tid] = S_h[cur][b][tid];
    }
    __syncthreads();
    {
      int qq = tid>>6, o = tid&63;
      float sacc = 0.f;
      for (int k2=qq*64;k2<qq*64+64;k2+=8){
        #pragma unroll
        for (int u=0;u<8;u++) sacc += sh.f.vin[k2+u]*W_out[(size_t)(k2+u)*OUTn + o];
      }
      sh.f.part[qq][0][o] = sacc;
    }
    __syncthreads();
    if (tid < 64){
      float sv = b_out[tid];
      #pragma unroll
      for (int qq=0;qq<8;qq++) sv += sh.f.part[qq][0][tid];
      outp[((size_t)t*Bn + b)*OUTn + tid] = clipv(sv);
    }
    __syncthreads();
    if (tid==0) sig_release(&g_fin[0]);

  } else {
    // ================= gates: compute gates(t+1), split part1/part2 =======
    if (t+1 >= Tn) return;
    const int jt = bid - 320;
    const int j = jt*64 + lane;
    const int b0 = wvi*4;
    const int hp = cur;               // slot of h(t)
    float bias = b_lstm[j];
    float a0=bias, a1=bias, a2=bias, a3=bias;
    // part1: x(t+1) + h(t)  (h ready right after phaseA's LSTM)
    wait_acq1(&g_hh[0], 32u*(unsigned)(t+1));
    for (int c=0;c<5;++c){
      #pragma unroll
      for (int u=0;u<4;u++){
        int e = u*512 + tid;
        int b2 = e >> 6, kk = e & 63;
        float v;
        if (c==0) v = xin[((size_t)(t+1)*Bn + b2)*INn + kk];
        else      v = S_h[hp][b2][(c-1)*64 + kk];
        sh.g.ctrl[b2][kk] = v;
      }
      __syncthreads();
      const float* wb = (c==0) ? (Wx + j)
                               : (Wh + (size_t)((c-1)*64)*G4H + j);
      #pragma unroll
      for (int kk=0;kk<64;kk++){
        float wv = wb[(size_t)kk*G4H];
        a0 += sh.g.ctrl[b0+0][kk]*wv;
        a1 += sh.g.ctrl[b0+1][kk]*wv;
        a2 += sh.g.ctrl[b0+2][kk]*wv;
        a3 += sh.g.ctrl[b0+3][kk]*wv;
      }
      __syncthreads();
    }
    // part2: reads(t) (after all fins)
    wait_acq1(&g_fin[0], 32u*(unsigned)(t+1));
    for (int c=0;c<4;++c){
      #pragma unroll
      for (int u=0;u<4;u++){
        int e = u*512 + tid;
        int b2 = e >> 6, kk = e & 63;
        sh.g.ctrl[b2][kk] = ((const float*)S_reads[b2])[c*64 + kk];
      }
      __syncthreads();
      const float* wb = Wx + (size_t)(INn + c*64)*G4H + j;
      #pragma unroll
      for (int kk=0;kk<64;kk++){
        float wv = wb[(size_t)kk*G4H];
        a0 += sh.g.ctrl[b0+0][kk]*wv;
        a1 += sh.g.ctrl[b0+1][kk]*wv;
        a2 += sh.g.ctrl[b0+2][kk]*wv;
        a3 += sh.g.ctrl[b0+3][kk]*wv;
      }
      __syncthreads();
    }
    const int gs = (t+1)&1;
    S_gates[gs][b0+0][j]=a0;
    S_gates[gs][b0+1][j]=a1;
    S_gates[gs][b0+2][j]=a2;
    S_gates[gs][b0+3][j]=a3;
  }
}

extern "C" void kernel_launch(void* const* d_in, const int* in_sizes, int n_in,
                              void* d_out, int out_size, void* d_ws, size_t ws_size,
                              hipStream_t stream){
  (void)in_sizes; (void)n_in; (void)d_ws; (void)ws_size; (void)out_size;
  const float* xin = (const float*)d_in[0];
  const float* Wx  = (const float*)d_in[1];
  const float* Wh  = (const float*)d_in[2];
  const float* bl  = (const float*)d_in[3];
  const float* Wif = (const float*)d_in[4];
  const float* bif = (const float*)d_in[5];
  const float* Wo  = (const float*)d_in[6];
  const float* bo  = (const float*)d_in[7];
  hipLaunchKernelGGL(k_init, dim3(1024), dim3(256), 0, stream);
  hipLaunchKernelGGL(k_gates_pro, dim3(16), dim3(512), 0, stream, xin, Wx, Wh, bl);
  for (int t=0; t<Tn; ++t){
    hipLaunchKernelGGL(k_step, dim3(336), dim3(512), 0, stream,
                       t, xin, Wx, Wh, bl, Wif, bif, Wo, bo, (float*)d_out);
  }
}

// Round 8
// 6271.306 us; speedup vs baseline: 2.3916x; 1.0121x over previous
//
#include <hip/hip_runtime.h>
#include <math.h>

#define Tn 64
#define Bn 32
#define INn 64
#define Nn 512
#define WDn 64
#define Rn 4
#define Hn 256
#define G4H 1024
#define OUTn 64
#define IFn 471
#define CLIPV 20.0f
#define EPSV 1e-6f

#define OFF_RKEY 0
#define OFF_RSTR 256
#define OFF_WKEY 260
#define OFF_WSTR 324
#define OFF_ERASE 325
#define OFF_WVEC 389
#define OFF_FREE 453
#define OFF_AG 457
#define OFF_WG 458
#define OFF_MODES 459

// ---------------- persistent device state ----------------
__device__ float S_h[2][Bn][Hn];          // h(t) in slot t&1
__device__ float S_c[2][Bn][Hn];
__device__ float S_gates[2][Bn][G4H];     // raw gates(t) in slot t&1
__device__ float S_mem[Bn][Nn][WDn];
__device__ float S_rw[Bn][Rn][Nn];        // rw(t), written by AF(t) tail
__device__ float S_ww[2][Bn][Nn];
__device__ float S_link[Bn][Nn][Nn];
__device__ float S_prec[2][Bn][Nn];
__device__ float S_usage[2][Bn][Nn];
__device__ float S_reads[Bn][Rn][WDn];
__device__ float S_itf[Bn][IFn];          // written 8-way by link blocks
__device__ float S_wsim[Bn][Nn];          // write-content sims, 8-way
__device__ float S_fw[Bn][Rn][Nn];
__device__ float S_bwp[Bn][8][Rn*Nn];
__device__ float S_sumww[Bn];
// monotonic flags, padded to 64B lines
__device__ unsigned int g_hh[16];         // 32*(t+1): all h(t) written
__device__ unsigned int g_hb[Bn][16];     // t+1: h(t) for batch b written
__device__ unsigned int g_itf[Bn][16];    // 8*(t+1): itf(b) slices done
__device__ unsigned int g_sim[Bn][16];    // 8*(t+1): wc sims(b) done
__device__ unsigned int g_ww[Bn][16];     // t+1: ww(b) ready
__device__ unsigned int g_ld[Bn][16];     // 8*(t+1): link(b) done
__device__ unsigned int g_fin[16];        // 32*(t+1): all AF tails done

// ---------------- helpers ----------------
__device__ __forceinline__ float sigm(float x){ return 1.f/(1.f+expf(-x)); }
__device__ __forceinline__ float clipv(float x){ return fminf(fmaxf(x,-CLIPV),CLIPV); }
__device__ __forceinline__ float oneplusf(float x){
  float sp = (x > 0.f) ? (x + log1pf(expf(-x))) : log1pf(expf(x));
  return 1.f + sp;
}
__device__ __forceinline__ float wredsum(float v){
  #pragma unroll
  for (int o=32;o>0;o>>=1) v += __shfl_xor(v,o,64);
  return v;
}
__device__ __forceinline__ float bredsum(float v, volatile float* scr){
  v = wredsum(v);
  if ((threadIdx.x & 63) == 0) scr[threadIdx.x >> 6] = v;
  __syncthreads();
  float s = scr[0];
  #pragma unroll
  for (int i=1;i<8;i++) s += scr[i];
  __syncthreads();
  return s;
}
__device__ __forceinline__ float bredmax(float v, volatile float* scr){
  #pragma unroll
  for (int o=32;o>0;o>>=1) v = fmaxf(v,__shfl_xor(v,o,64));
  if ((threadIdx.x & 63) == 0) scr[threadIdx.x >> 6] = v;
  __syncthreads();
  float m = scr[0];
  #pragma unroll
  for (int i=1;i<8;i++) m = fmaxf(m, scr[i]);
  __syncthreads();
  return m;
}
__device__ __forceinline__ void sig_release(unsigned int* flag){
  __builtin_amdgcn_fence(__ATOMIC_RELEASE, "agent");
  __hip_atomic_fetch_add(flag, 1u, __ATOMIC_RELAXED, __HIP_MEMORY_SCOPE_AGENT);
}
__device__ __forceinline__ void spin_until(unsigned int* flag, unsigned int target){
  while (__hip_atomic_load(flag, __ATOMIC_RELAXED, __HIP_MEMORY_SCOPE_AGENT) < target)
    __builtin_amdgcn_s_sleep(1);
}
__device__ __forceinline__ void wait_acq1(unsigned int* f, unsigned int tgt){
  if (threadIdx.x==0){
    spin_until(f, tgt);
    __builtin_amdgcn_fence(__ATOMIC_ACQUIRE, "agent");
  }
  __syncthreads();
}

// ================= init =================
extern "C" __global__ void __launch_bounds__(256)
k_init(){
  size_t g = (size_t)blockIdx.x*256 + threadIdx.x;
  size_t stride = (size_t)gridDim.x*256;
  float* lk = &S_link[0][0][0];
  for (size_t i=g; i<(size_t)Bn*Nn*Nn; i+=stride) lk[i]=0.f;
  float* mm = &S_mem[0][0][0];
  for (size_t i=g; i<(size_t)Bn*Nn*WDn; i+=stride) mm[i]=0.f;
  float* rr = &S_rw[0][0][0];
  for (size_t i=g; i<(size_t)Bn*Rn*Nn; i+=stride) rr[i]=0.f;
  float* rd = &S_reads[0][0][0];
  for (size_t i=g; i<(size_t)Bn*Rn*WDn; i+=stride) rd[i]=0.f;
  for (size_t i=g; i<(size_t)2*Bn*Nn; i+=stride){
    S_ww[0][0][i]=0.f; S_prec[0][0][i]=0.f; S_usage[0][0][i]=0.f;
  }
  for (size_t i=g; i<(size_t)2*Bn*Hn; i+=stride){
    S_h[0][0][i]=0.f; S_c[0][0][i]=0.f;
  }
  if (blockIdx.x==0){
    for (int i=threadIdx.x; i<16; i+=256){ g_hh[i]=0u; g_fin[i]=0u; }
    for (int i=threadIdx.x; i<Bn*16; i+=256){
      ((unsigned int*)g_hb)[i]=0u; ((unsigned int*)g_itf)[i]=0u;
      ((unsigned int*)g_sim)[i]=0u; ((unsigned int*)g_ww)[i]=0u;
      ((unsigned int*)g_ld)[i]=0u;
    }
  }
}

// ================= shared-mem role layouts =================
struct ShG { float ctrl[Bn][65]; };
struct ShAF {
  float itf[IFn];
  float ww[Nn];
  float red[8];
  float betar[Rn], knr[Rn], modes[Rn][4];
  float er[WDn], wv[WDn], rk[Rn][WDn];
  union {
    struct { unsigned long long keys[Nn]; float alloc[Nn]; float wsim[Nn]; } pre;
    struct {
      float tile[64][65];
      float rsim[Rn][Nn];
      float fw[Rn][Nn];
      float bw[Rn][Nn];
      float part[8][Rn][WDn];
      float vin[512];
    } post;
  } u;
};
struct ShL {
  float hc[Hn];
  float ipart[8][64];
  float wkey[WDn];
  float knw, betaw;
  float ww[Nn];
  float prec[Nn];
  float rw[Rn][Nn];
  float bwp4[4][Rn][Nn];
};
union ShU { ShAF a; ShL l; ShG g; };

// ================= gates prologue: gates(0) =================
extern "C" __global__ void __launch_bounds__(512)
k_gates_pro(const float* __restrict__ xin, const float* __restrict__ Wx,
            const float* __restrict__ Wh, const float* __restrict__ b_lstm){
  __shared__ ShG sg;
  const int tid = threadIdx.x, lane = tid & 63, wvi = tid >> 6;
  const int j = blockIdx.x*64 + lane;
  const int b0 = wvi*4;
  float bias = b_lstm[j];
  float a0=bias, a1=bias, a2=bias, a3=bias;
  // only x contributes at t=0 (reads=h=0)
  {
    #pragma unroll
    for (int u=0;u<4;u++){
      int e = u*512 + tid;
      int b2 = e >> 6, kk = e & 63;
      sg.ctrl[b2][kk] = xin[(size_t)b2*INn + kk];
    }
    __syncthreads();
    const float* wb = Wx + j;
    #pragma unroll
    for (int kk=0;kk<64;kk++){
      float wv = wb[(size_t)kk*G4H];
      a0 += sg.ctrl[b0+0][kk]*wv;
      a1 += sg.ctrl[b0+1][kk]*wv;
      a2 += sg.ctrl[b0+2][kk]*wv;
      a3 += sg.ctrl[b0+3][kk]*wv;
    }
  }
  S_gates[0][b0+0][j]=a0;
  S_gates[0][b0+1][j]=a1;
  S_gates[0][b0+2][j]=a2;
  S_gates[0][b0+3][j]=a3;
}

// ================= per-step kernel: 304 blocks x 512 =================
extern "C" __global__ void __launch_bounds__(512, 4)
k_step(int t, const float* __restrict__ xin,
       const float* __restrict__ Wx, const float* __restrict__ Wh,
       const float* __restrict__ b_lstm,
       const float* __restrict__ W_if, const float* __restrict__ b_if,
       const float* __restrict__ W_out, const float* __restrict__ b_out,
       float* __restrict__ outp){
  __shared__ ShU sh;
  const int tid = threadIdx.x;
  const int lane = tid & 63, wvi = tid >> 6;
  const int bid = blockIdx.x;
  const int cur = t&1, prev = cur^1;

  if (bid < 32){
    // ================= AF role: LSTM -> (usage/alloc) -> ww -> mem/rc -> tail
    const int b = bid;
    // LSTM combine from raw gates (written last dispatch / prologue)
    if (tid < Hn){
      int h = tid;
      float g0=S_gates[cur][b][h],     g1=S_gates[cur][b][Hn+h];
      float g2=S_gates[cur][b][2*Hn+h],g3=S_gates[cur][b][3*Hn+h];
      float cold = S_c[prev][b][h];
      float cn = sigm(g1)*cold + sigm(g0)*tanhf(g2);
      float hn = sigm(g3)*tanhf(cn);
      S_c[cur][b][h] = clipv(cn);
      S_h[cur][b][h] = clipv(hn);
    }
    __syncthreads();
    if (tid==0){ sig_release(&g_hb[b][0]); sig_release(&g_hh[0]); }
    // wait itf(b) computed 8-way by link blocks
    wait_acq1(&g_itf[b][0], 8u*(unsigned)(t+1));
    for (int k=tid;k<IFn;k+=512) sh.a.itf[k] = S_itf[b][k];
    __syncthreads();
    // fin staging + usage/keys
    if (tid < WDn){
      sh.a.er[tid] = sigm(sh.a.itf[OFF_ERASE+tid]);
      sh.a.wv[tid] = sh.a.itf[OFF_WVEC+tid];
    } else if (tid < WDn + Rn*WDn){
      int k2 = tid - WDn;
      sh.a.rk[k2>>6][k2&63] = sh.a.itf[OFF_RKEY + k2];
    } else if (tid < WDn + Rn*WDn + Rn){
      int r = tid - (WDn+Rn*WDn);
      sh.a.betar[r] = oneplusf(sh.a.itf[OFF_RSTR + r]);
    } else if (tid >= 384 && tid < 384+Rn){
      int r = tid - 384;
      float m0 = sh.a.itf[OFF_MODES + r*3 + 0];
      float m1 = sh.a.itf[OFF_MODES + r*3 + 1];
      float m2 = sh.a.itf[OFF_MODES + r*3 + 2];
      float mx = fmaxf(m0,fmaxf(m1,m2));
      float e0=expf(m0-mx), e1=expf(m1-mx), e2=expf(m2-mx);
      float si = e0+e1+e2;
      sh.a.modes[r][0]=e0/si; sh.a.modes[r][1]=e1/si; sh.a.modes[r][2]=e2/si;
    }
    // usage update + stable-sort key (all threads, n = tid)
    {
      float fg0=sigm(sh.a.itf[OFF_FREE+0]), fg1=sigm(sh.a.itf[OFF_FREE+1]);
      float fg2=sigm(sh.a.itf[OFF_FREE+2]), fg3=sigm(sh.a.itf[OFF_FREE+3]);
      int n = tid;
      float uu = S_usage[prev][b][n], wwp = S_ww[prev][b][n];
      float u = uu + (1.f-uu)*wwp;
      float psi = (1.f - fg0*S_rw[b][0][n])*(1.f - fg1*S_rw[b][1][n])
                * (1.f - fg2*S_rw[b][2][n])*(1.f - fg3*S_rw[b][3][n]);
      float un = u*psi;
      S_usage[cur][b][n] = un;
      float v = EPSV + (1.f-EPSV)*un;
      sh.a.u.pre.keys[n] = ((unsigned long long)__float_as_uint(v) << 32) | (unsigned)n;
    }
    __syncthreads();
    // read-key norms (waves 0-3)
    if (wvi < 4){
      float kv = sh.a.rk[wvi][lane];
      float s2 = wredsum(kv*kv);
      if (lane==0) sh.a.knr[wvi] = sqrtf(s2);
    }
    // sort-free allocation: a_i = (1-u_i) * prod_{key_j < key_i} u_j
    {
      unsigned long long myk = sh.a.u.pre.keys[tid];
      float prod = 1.f;
      for (int j=0;j<Nn;j+=8){
        #pragma unroll
        for (int u=0;u<8;u++){
          unsigned long long kj = sh.a.u.pre.keys[j+u];
          float uj = __uint_as_float((unsigned)(kj>>32));
          prod *= (kj < myk) ? uj : 1.f;
        }
      }
      float myu = __uint_as_float((unsigned)(myk>>32));
      sh.a.u.pre.alloc[tid] = (1.f - myu)*prod;
    }
    // wait write-content sims (computed 8-way by link blocks)
    wait_acq1(&g_sim[b][0], 8u*(unsigned)(t+1));
    sh.a.u.pre.wsim[tid] = S_wsim[b][tid];
    __syncthreads();
    // softmax -> wc ; ww ; sumww
    {
      float v = sh.a.u.pre.wsim[tid];
      float mx = bredmax(v, sh.a.red);
      float e = expf(v - mx);
      float ssum = bredsum(e, sh.a.red);
      float wc = e/ssum;
      float ag = sigm(sh.a.itf[OFF_AG]);
      float wg = sigm(sh.a.itf[OFF_WG]);
      float wwv = wg*(ag*sh.a.u.pre.alloc[tid] + (1.f-ag)*wc);
      S_ww[cur][b][tid] = wwv;
      sh.a.ww[tid] = wwv;
      float wsum = bredsum(wwv, sh.a.red);
      if (tid==0) S_sumww[b] = wsum;
    }
    __syncthreads();
    if (tid==0) sig_release(&g_ww[b][0]);
    // mem erase/write + read-content sims (overlaps link role)
    for (int tile=0;tile<8;tile++){
      #pragma unroll
      for (int u=0;u<8;u++){
        int e = u*512 + tid;
        int nn = e>>6, w = e&63;
        int n = tile*64+nn;
        float m = S_mem[b][n][w];
        float wwn = sh.a.ww[n];
        m = m*(1.f - wwn*sh.a.er[w]) + wwn*sh.a.wv[w];
        S_mem[b][n][w] = m;
        sh.a.u.post.tile[nn][w] = m;
      }
      __syncthreads();
      {
        int nn = tid>>3, qq = tid&7;
        float a0=0.f,a1=0.f,a2=0.f,a3=0.f,nrm=0.f;
        #pragma unroll
        for (int i=0;i<8;i++){
          int w = qq*8+i;
          float m = sh.a.u.post.tile[nn][w];
          a0 += m*sh.a.rk[0][w]; a1 += m*sh.a.rk[1][w];
          a2 += m*sh.a.rk[2][w]; a3 += m*sh.a.rk[3][w];
          nrm += m*m;
        }
        #pragma unroll
        for (int o=1;o<8;o<<=1){
          a0 += __shfl_xor(a0,o,64); a1 += __shfl_xor(a1,o,64);
          a2 += __shfl_xor(a2,o,64); a3 += __shfl_xor(a3,o,64);
          nrm += __shfl_xor(nrm,o,64);
        }
        if (qq==0){
          int n = tile*64+nn;
          float mn = sqrtf(nrm);
          sh.a.u.post.rsim[0][n] = sh.a.betar[0]*a0/(sh.a.knr[0]*mn + EPSV);
          sh.a.u.post.rsim[1][n] = sh.a.betar[1]*a1/(sh.a.knr[1]*mn + EPSV);
          sh.a.u.post.rsim[2][n] = sh.a.betar[2]*a2/(sh.a.knr[2]*mn + EPSV);
          sh.a.u.post.rsim[3][n] = sh.a.betar[3]*a3/(sh.a.knr[3]*mn + EPSV);
        }
      }
      __syncthreads();
    }
    // rc softmax per head (in place)
    for (int r=0;r<Rn;r++){
      float v = sh.a.u.post.rsim[r][tid];
      float mx = bredmax(v, sh.a.red);
      float e = expf(v - mx);
      float ssum = bredsum(e, sh.a.red);
      sh.a.u.post.rsim[r][tid] = e/ssum;
    }
    __syncthreads();
    // wait link, combine rw
    wait_acq1(&g_ld[b][0], 8u*(unsigned)(t+1));
    for (int k=tid;k<Rn*Nn;k+=512){
      ((float*)sh.a.u.post.fw)[k] = ((const float*)S_fw[b])[k];
      float sbw = 0.f;
      #pragma unroll
      for (int ch=0;ch<8;ch++) sbw += S_bwp[b][ch][k];
      ((float*)sh.a.u.post.bw)[k] = sbw;
    }
    __syncthreads();
    for (int k=tid;k<Rn*Nn;k+=512){
      int r = k>>9, n = k&511;
      float v = sh.a.modes[r][2]*sh.a.u.post.rsim[r][n]
              + sh.a.modes[r][1]*sh.a.u.post.fw[r][n]
              + sh.a.modes[r][0]*sh.a.u.post.bw[r][n];
      sh.a.u.post.rsim[r][n] = v;
      S_rw[b][r][n] = v;
    }
    __syncthreads();
    // reads = rw @ mem  (mem L2-hot from the update pass)
    {
      float a0=0.f,a1=0.f,a2=0.f,a3=0.f;
      #pragma unroll 4
      for (int nn=0;nn<64;nn++){
        int n = wvi*64+nn;
        float m = S_mem[b][n][lane];
        a0 += sh.a.u.post.rsim[0][n]*m; a1 += sh.a.u.post.rsim[1][n]*m;
        a2 += sh.a.u.post.rsim[2][n]*m; a3 += sh.a.u.post.rsim[3][n]*m;
      }
      sh.a.u.post.part[wvi][0][lane]=a0; sh.a.u.post.part[wvi][1][lane]=a1;
      sh.a.u.post.part[wvi][2][lane]=a2; sh.a.u.post.part[wvi][3][lane]=a3;
    }
    __syncthreads();
    if (tid < 256){
      int r = tid>>6, w = tid&63;
      float sv = 0.f;
      #pragma unroll
      for (int v=0;v<8;v++) sv += sh.a.u.post.part[v][r][w];
      S_reads[b][r][w] = sv;
      sh.a.u.post.vin[256+tid] = sv;
      sh.a.u.post.vin[tid] = S_h[cur][b][tid];
    }
    __syncthreads();
    {
      int qq = tid>>6, o = tid&63;
      float sacc = 0.f;
      for (int k2=qq*64;k2<qq*64+64;k2+=8){
        #pragma unroll
        for (int u=0;u<8;u++) sacc += sh.a.u.post.vin[k2+u]*W_out[(size_t)(k2+u)*OUTn + o];
      }
      sh.a.u.post.part[qq][0][o] = sacc;
    }
    __syncthreads();
    if (tid < 64){
      float sv = b_out[tid];
      #pragma unroll
      for (int qq=0;qq<8;qq++) sv += sh.a.u.post.part[qq][0][tid];
      outp[((size_t)t*Bn + b)*OUTn + tid] = clipv(sv);
    }
    __syncthreads();
    if (tid==0) sig_release(&g_fin[0]);

  } else if (bid < 288){
    // ================= link role: itf-assist + wc-sim + link =================
    const int idx = bid - 32;
    const int b = idx >> 3, ch = idx & 7;
    const int i0 = ch*64;
    // --- itf assist: compute itf[b][ch*59 .. ] ---
    wait_acq1(&g_hb[b][0], (unsigned)(t+1));
    if (tid < Hn) sh.l.hc[tid] = S_h[cur][b][tid];
    __syncthreads();
    const int col0 = ch*59;
    const int ncol = (col0+59 <= IFn) ? 59 : (IFn - col0);
    {
      float acc = 0.f;
      if (lane < ncol){
        const float* wp = W_if + (size_t)(wvi*32)*IFn + col0 + lane;
        #pragma unroll
        for (int kk=0;kk<32;kk++)
          acc += sh.l.hc[wvi*32+kk]*wp[(size_t)kk*IFn];
      }
      sh.l.ipart[wvi][lane] = acc;
    }
    __syncthreads();
    if (tid < ncol){
      float s = b_if[col0+tid];
      #pragma unroll
      for (int w=0;w<8;w++) s += sh.l.ipart[w][tid];
      S_itf[b][col0+tid] = s;
    }
    __syncthreads();
    if (tid==0) sig_release(&g_itf[b][0]);
    // --- wc-sim for own 64 rows ---
    wait_acq1(&g_itf[b][0], 8u*(unsigned)(t+1));
    if (tid < WDn) sh.l.wkey[tid] = S_itf[b][OFF_WKEY+tid];
    else if (tid==64) sh.l.betaw = oneplusf(S_itf[b][OFF_WSTR]);
    __syncthreads();
    if (wvi==0){
      float kv = sh.l.wkey[lane];
      float s2 = wredsum(kv*kv);
      if (lane==0) sh.l.knw = sqrtf(s2);
    }
    __syncthreads();
    {
      int nn = tid>>3, qq = tid&7;
      int n = i0 + nn;
      const float4* mp = (const float4*)(&S_mem[b][n][qq*8]);
      float4 ma = mp[0], mb = mp[1];
      float d, nrm;
      {
        float k0=sh.l.wkey[qq*8+0], k1=sh.l.wkey[qq*8+1], k2=sh.l.wkey[qq*8+2], k3=sh.l.wkey[qq*8+3];
        float k4=sh.l.wkey[qq*8+4], k5=sh.l.wkey[qq*8+5], k6=sh.l.wkey[qq*8+6], k7=sh.l.wkey[qq*8+7];
        d   = ma.x*k0+ma.y*k1+ma.z*k2+ma.w*k3 + mb.x*k4+mb.y*k5+mb.z*k6+mb.w*k7;
        nrm = ma.x*ma.x+ma.y*ma.y+ma.z*ma.z+ma.w*ma.w
            + mb.x*mb.x+mb.y*mb.y+mb.z*mb.z+mb.w*mb.w;
      }
      #pragma unroll
      for (int o=1;o<8;o<<=1){ d += __shfl_xor(d,o,64); nrm += __shfl_xor(nrm,o,64); }
      if (qq==0)
        S_wsim[b][n] = sh.l.betaw * d / (sh.l.knw*sqrtf(nrm) + EPSV);
    }
    __syncthreads();
    if (tid==0) sig_release(&g_sim[b][0]);
    // --- link pass ---
    wait_acq1(&g_ww[b][0], (unsigned)(t+1));
    sh.l.ww[tid]   = S_ww[cur][b][tid];
    sh.l.prec[tid] = S_prec[prev][b][tid];
    for (int k=tid;k<Rn*Nn;k+=512) ((float*)sh.l.rw)[k] = ((const float*)S_rw[b])[k];
    __syncthreads();
    float sumww = S_sumww[b];
    float wj[2][4], pj[2][4], rj[4][2][4];
    #pragma unroll
    for (int jjc=0;jjc<2;jjc++){
      float4 w4 = ((const float4*)sh.l.ww)[jjc*64+lane];
      float4 p4 = ((const float4*)sh.l.prec)[jjc*64+lane];
      wj[jjc][0]=w4.x; wj[jjc][1]=w4.y; wj[jjc][2]=w4.z; wj[jjc][3]=w4.w;
      pj[jjc][0]=p4.x; pj[jjc][1]=p4.y; pj[jjc][2]=p4.z; pj[jjc][3]=p4.w;
      #pragma unroll
      for (int r=0;r<4;r++){
        float4 r4 = ((const float4*)sh.l.rw[r])[jjc*64+lane];
        rj[r][jjc][0]=r4.x; rj[r][jjc][1]=r4.y; rj[r][jjc][2]=r4.z; rj[r][jjc][3]=r4.w;
      }
    }
    float bwa[4][2][4];
    #pragma unroll
    for (int r=0;r<4;r++)
      #pragma unroll
      for (int jjc=0;jjc<2;jjc++)
        #pragma unroll
        for (int s=0;s<4;s++) bwa[r][jjc][s]=0.f;
    for (int rr=0;rr<8;rr++){
      const int i = i0 + wvi*8 + rr;
      float wi = sh.l.ww[i];
      float ci = 1.f - wi;
      float ri[4] = {sh.l.rw[0][i], sh.l.rw[1][i], sh.l.rw[2][i], sh.l.rw[3][i]};
      float f[4] = {0.f,0.f,0.f,0.f};
      float4* lrow4 = (float4*)(&S_link[b][i][0]);
      #pragma unroll
      for (int jjc=0;jjc<2;jjc++){
        float4 L4 = lrow4[jjc*64+lane];
        float Ls[4] = {L4.x, L4.y, L4.z, L4.w};
        #pragma unroll
        for (int s=0;s<4;s++){
          float Ln = (ci - wj[jjc][s])*Ls[s] + wi*pj[jjc][s];
          int j = jjc*256 + lane*4 + s;
          Ln = (j==i) ? 0.f : Ln;
          Ls[s] = Ln;
          #pragma unroll
          for (int r=0;r<4;r++){
            f[r] += Ln*rj[r][jjc][s];
            bwa[r][jjc][s] += Ln*ri[r];
          }
        }
        float4 Lo; Lo.x=Ls[0]; Lo.y=Ls[1]; Lo.z=Ls[2]; Lo.w=Ls[3];
        lrow4[jjc*64+lane] = Lo;
      }
      #pragma unroll
      for (int r=0;r<4;r++){
        float fr = wredsum(f[r]);
        if (lane==0) S_fw[b][r][i] = fr;
      }
    }
    if (wvi < 4){
      #pragma unroll
      for (int r=0;r<4;r++)
        #pragma unroll
        for (int jjc=0;jjc<2;jjc++){
          float4 v4; v4.x=bwa[r][jjc][0]; v4.y=bwa[r][jjc][1]; v4.z=bwa[r][jjc][2]; v4.w=bwa[r][jjc][3];
          ((float4*)sh.l.bwp4[wvi][r])[jjc*64+lane] = v4;
        }
    }
    __syncthreads();
    if (wvi >= 4){
      int v = wvi-4;
      #pragma unroll
      for (int r=0;r<4;r++)
        #pragma unroll
        for (int jjc=0;jjc<2;jjc++){
          float4 v4 = ((float4*)sh.l.bwp4[v][r])[jjc*64+lane];
          v4.x+=bwa[r][jjc][0]; v4.y+=bwa[r][jjc][1]; v4.z+=bwa[r][jjc][2]; v4.w+=bwa[r][jjc][3];
          ((float4*)sh.l.bwp4[v][r])[jjc*64+lane] = v4;
        }
    }
    __syncthreads();
    for (int k=tid;k<Rn*Nn;k+=512){
      float s = ((float*)sh.l.bwp4[0])[k] + ((float*)sh.l.bwp4[1])[k]
              + ((float*)sh.l.bwp4[2])[k] + ((float*)sh.l.bwp4[3])[k];
      S_bwp[b][ch][k] = s;
    }
    if (tid < 64){
      int j = i0 + tid;
      S_prec[cur][b][j] = (1.f - sumww)*sh.l.prec[j] + sh.l.ww[j];
    }
    __syncthreads();
    if (tid==0) sig_release(&g_ld[b][0]);

  } else {
    // ================= gates: compute gates(t+1), split part1/part2 =======
    if (t+1 >= Tn) return;
    const int jt = bid - 288;
    const int j = jt*64 + lane;
    const int b0 = wvi*4;
    const int hp = cur;               // slot of h(t)
    float bias = b_lstm[j];
    float a0=bias, a1=bias, a2=bias, a3=bias;
    // part1: x(t+1) + h(t)
    wait_acq1(&g_hh[0], 32u*(unsigned)(t+1));
    for (int c=0;c<5;++c){
      #pragma unroll
      for (int u=0;u<4;u++){
        int e = u*512 + tid;
        int b2 = e >> 6, kk = e & 63;
        float v;
        if (c==0) v = xin[((size_t)(t+1)*Bn + b2)*INn + kk];
        else      v = S_h[hp][b2][(c-1)*64 + kk];
        sh.g.ctrl[b2][kk] = v;
      }
      __syncthreads();
      const float* wb = (c==0) ? (Wx + j)
                               : (Wh + (size_t)((c-1)*64)*G4H + j);
      #pragma unroll
      for (int kk=0;kk<64;kk++){
        float wv = wb[(size_t)kk*G4H];
        a0 += sh.g.ctrl[b0+0][kk]*wv;
        a1 += sh.g.ctrl[b0+1][kk]*wv;
        a2 += sh.g.ctrl[b0+2][kk]*wv;
        a3 += sh.g.ctrl[b0+3][kk]*wv;
      }
      __syncthreads();
    }
    // part2: reads(t)
    wait_acq1(&g_fin[0], 32u*(unsigned)(t+1));
    for (int c=0;c<4;++c){
      #pragma unroll
      for (int u=0;u<4;u++){
        int e = u*512 + tid;
        int b2 = e >> 6, kk = e & 63;
        sh.g.ctrl[b2][kk] = ((const float*)S_reads[b2])[c*64 + kk];
      }
      __syncthreads();
      const float* wb = Wx + (size_t)(INn + c*64)*G4H + j;
      #pragma unroll
      for (int kk=0;kk<64;kk++){
        float wv = wb[(size_t)kk*G4H];
        a0 += sh.g.ctrl[b0+0][kk]*wv;
        a1 += sh.g.ctrl[b0+1][kk]*wv;
        a2 += sh.g.ctrl[b0+2][kk]*wv;
        a3 += sh.g.ctrl[b0+3][kk]*wv;
      }
      __syncthreads();
    }
    const int gs = (t+1)&1;
    S_gates[gs][b0+0][j]=a0;
    S_gates[gs][b0+1][j]=a1;
    S_gates[gs][b0+2][j]=a2;
    S_gates[gs][b0+3][j]=a3;
  }
}

extern "C" void kernel_launch(void* const* d_in, const int* in_sizes, int n_in,
                              void* d_out, int out_size, void* d_ws, size_t ws_size,
                              hipStream_t stream){
  (void)in_sizes; (void)n_in; (void)d_ws; (void)ws_size; (void)out_size;
  const float* xin = (const float*)d_in[0];
  const float* Wx  = (const float*)d_in[1];
  const float* Wh  = (const float*)d_in[2];
  const float* bl  = (const float*)d_in[3];
  const float* Wif = (const float*)d_in[4];
  const float* bif = (const float*)d_in[5];
  const float* Wo  = (const float*)d_in[6];
  const float* bo  = (const float*)d_in[7];
  hipLaunchKernelGGL(k_init, dim3(1024), dim3(256), 0, stream);
  hipLaunchKernelGGL(k_gates_pro, dim3(16), dim3(512), 0, stream, xin, Wx, Wh, bl);
  for (int t=0; t<Tn; ++t){
    hipLaunchKernelGGL(k_step, dim3(304), dim3(512), 0, stream,
                       t, xin, Wx, Wh, bl, Wif, bif, Wo, bo, (float*)d_out);
  }
}